// Round 5
// baseline (310.009 us; speedup 1.0000x reference)
//
#include <hip/hip_runtime.h>
#include <stdint.h>

#define S_   512
#define E_   512
#define CIN  1536
#define P_   32768
#define OUTC 512
#define LDP  40   // padded LDS stride (shorts) for register-staged gemm_g

typedef __attribute__((ext_vector_type(8))) short s16x8;   // MFMA A/B frag (8 bf16)
typedef __attribute__((ext_vector_type(4))) float f32x4;   // MFMA C/D frag
typedef unsigned short ushort_t;

__device__ __forceinline__ float b2f(uint32_t b) {
    union { uint32_t u; float f; } v; v.u = b << 16; return v.f;
}
__device__ __forceinline__ uint32_t f2b(float f) {   // fp32 -> bf16 bits, RNE
    union { float f; uint32_t u; } v; v.f = f;
    return (v.u + 0x7fffu + ((v.u >> 16) & 1u)) >> 16;
}
__device__ __forceinline__ uint4 cvt8(float4 a, float4 b) {
    uint4 r;
    r.x = f2b(a.x) | (f2b(a.y) << 16);
    r.y = f2b(a.z) | (f2b(a.w) << 16);
    r.z = f2b(b.x) | (f2b(b.y) << 16);
    r.w = f2b(b.z) | (f2b(b.w) << 16);
    return r;
}
__device__ __forceinline__ void async16(const void* g, void* l) {
    __builtin_amdgcn_global_load_lds(
        (const __attribute__((address_space(1))) void*)g,
        (__attribute__((address_space(3))) void*)l, 16, 0, 0);
}
__device__ __forceinline__ void ins3(float d, int s,
                                     float& d0, int& i0, float& d1, int& i1,
                                     float& d2, int& i2)
{
    if (d < d2) {
        if (d < d1) {
            if (d < d0) { d2 = d1; i2 = i1; d1 = d0; i1 = i0; d0 = d; i0 = s; }
            else        { d2 = d1; i2 = i1; d1 = d;  i1 = s; }
        } else          { d2 = d;  i2 = s; }
    }
}

// ---------- 0) prep: W1,W2 fp32 -> bf16 ----------
__global__ __launch_bounds__(256) void prep_w(
    const float* __restrict__ W1f, const float* __restrict__ W2f,
    ushort_t* __restrict__ W1c, ushort_t* __restrict__ W2c)
{
    int v = blockIdx.x * 256 + threadIdx.x;          // vec4 index
    if (v < (OUTC * CIN / 4)) {
        const float4 x = ((const float4*)W1f)[v];
        uint2 o; o.x = f2b(x.x) | (f2b(x.y) << 16); o.y = f2b(x.z) | (f2b(x.w) << 16);
        ((uint2*)W1c)[v] = o;
    } else {
        v -= OUTC * CIN / 4;
        const float4 x = ((const float4*)W2f)[v];
        uint2 o; o.x = f2b(x.x) | (f2b(x.y) << 16); o.y = f2b(x.z) | (f2b(x.w) << 16);
        ((uint2*)W2c)[v] = o;
    }
}

// ---------- 1) kNN: 4 lanes per point, 128 centers each, shfl-xor merge ----------
__global__ __launch_bounds__(256) void knn_kernel(
    const float* __restrict__ xyz, const float* __restrict__ centers,
    int* __restrict__ idx_out, float* __restrict__ w_out)
{
    __shared__ float cx[S_], cy[S_], cz[S_], cc[S_];
    const int t = threadIdx.x;
    const int pBlock = blockIdx.x * 64;      // 64 points per block; 64 | 8192
    const int b = pBlock >> 13;
    for (int i = t; i < S_; i += 256) {
        const float x = centers[(size_t)(b * S_ + i) * 3 + 0];
        const float y = centers[(size_t)(b * S_ + i) * 3 + 1];
        const float z = centers[(size_t)(b * S_ + i) * 3 + 2];
        cx[i] = x; cy[i] = y; cz[i] = z; cc[i] = x * x + y * y + z * z;
    }
    __syncthreads();

    const int l4 = t & 3, pi = t >> 2;
    const int p = pBlock + pi;
    const float x = xyz[(size_t)p * 3 + 0];
    const float y = xyz[(size_t)p * 3 + 1];
    const float z = xyz[(size_t)p * 3 + 2];
    const float xx = x * x + y * y + z * z;

    float d0 = 3e38f, d1 = 3e38f, d2 = 3e38f;
    int   i0 = 0,     i1 = 0,     i2 = 0;
    const int sBeg = l4 * 128;
    for (int s = sBeg; s < sBeg + 128; ++s) {
        const float dot = x * cx[s] + y * cy[s] + z * cz[s];
        const float d = (xx - 2.0f * dot) + cc[s];   // mirror np association
        ins3(d, s, d0, i0, d1, i1, d2, i2);
    }
    // merge the 4 lane-local top-3 lists (xor 1 then xor 2)
#pragma unroll
    for (int m = 1; m <= 2; m <<= 1) {
        const float od0 = __shfl_xor(d0, m), od1 = __shfl_xor(d1, m), od2 = __shfl_xor(d2, m);
        const int   oi0 = __shfl_xor(i0, m), oi1 = __shfl_xor(i1, m), oi2 = __shfl_xor(i2, m);
        ins3(od0, oi0, d0, i0, d1, i1, d2, i2);
        ins3(od1, oi1, d0, i0, d1, i1, d2, i2);
        ins3(od2, oi2, d0, i0, d1, i1, d2, i2);
    }
    if (l4 == 0) {
        const float r0 = 1.0f / (d0 + 1e-8f);
        const float r1 = 1.0f / (d1 + 1e-8f);
        const float r2 = 1.0f / (d2 + 1e-8f);
        const float rs = r0 + r1 + r2;
        idx_out[p * 3 + 0] = i0; idx_out[p * 3 + 1] = i1; idx_out[p * 3 + 2] = i2;
        w_out[p * 3 + 0] = r0 / rs; w_out[p * 3 + 1] = r1 / rs; w_out[p * 3 + 2] = r2 / rs;
    }
}

// ---------- 2) G[b] = concat(H)[b](512x1536 fp32) x W1c^T -> fp32 [4,512,512] ----------
// 64x64 tiles -> 256 blocks (full GPU); register double-buffer prefetch.
__global__ __launch_bounds__(256) void gemm_g(
    const float* __restrict__ H4, const float* __restrict__ H8,
    const float* __restrict__ H12, const ushort_t* __restrict__ W1c,
    float* __restrict__ G)
{
    __shared__ ushort_t Asm[64 * LDP];   // 5 KB
    __shared__ ushort_t Bsm[64 * LDP];
    const int t = threadIdx.x, wave = t >> 6, lane = t & 63;
    const int wr = wave >> 1, wc = wave & 1, quad = lane >> 4, l15 = lane & 15;
    const int bb = blockIdx.z;
    const int colBase = blockIdx.x * 64, rowBase = blockIdx.y * 64;
    const size_t hb = (size_t)bb * S_ * E_;

    f32x4 acc[2][2];
    const f32x4 z4 = {0.f, 0.f, 0.f, 0.f};
#pragma unroll
    for (int i = 0; i < 2; ++i)
#pragma unroll
        for (int j = 0; j < 2; ++j) acc[i][j] = z4;

    const int ar = t >> 2, ac = (t & 3) * 8;   // 256 slots = 64 rows x 32 k

    float4 A0a, A0b; uint4 B0;
    auto loadTile = [&](int k0) {
        const float* Hs = ((k0 < 512) ? H4 : (k0 < 1024) ? H8 : H12) + hb;
        const int kc = (k0 & 511) + ac;
        const float* r0 = Hs + (size_t)(rowBase + ar) * E_ + kc;
        A0a = *(const float4*)r0;  A0b = *(const float4*)(r0 + 4);
        B0  = *(const uint4*)(W1c + (size_t)(colBase + ar) * CIN + k0 + ac);
    };
    loadTile(0);

    for (int k0 = 0; k0 < CIN; k0 += 32) {
        __syncthreads();
        *(uint4*)&Asm[ar * LDP + ac] = cvt8(A0a, A0b);
        *(uint4*)&Bsm[ar * LDP + ac] = B0;
        __syncthreads();
        if (k0 + 32 < CIN) loadTile(k0 + 32);   // prefetch overlaps frag reads + MFMA

        s16x8 af[2], bfr[2];
#pragma unroll
        for (int mi = 0; mi < 2; ++mi)
            af[mi] = *(const s16x8*)&Asm[(wr * 32 + mi * 16 + l15) * LDP + quad * 8];
#pragma unroll
        for (int ni = 0; ni < 2; ++ni)
            bfr[ni] = *(const s16x8*)&Bsm[(wc * 32 + ni * 16 + l15) * LDP + quad * 8];
#pragma unroll
        for (int mi = 0; mi < 2; ++mi)
#pragma unroll
            for (int ni = 0; ni < 2; ++ni)
                acc[mi][ni] = __builtin_amdgcn_mfma_f32_16x16x32_bf16(
                    af[mi], bfr[ni], acc[mi][ni], 0, 0, 0);
    }

#pragma unroll
    for (int mi = 0; mi < 2; ++mi) {
        const int row0 = rowBase + wr * 32 + mi * 16 + quad * 4;
#pragma unroll
        for (int ni = 0; ni < 2; ++ni) {
            const int col = colBase + wc * 32 + ni * 16 + l15;
#pragma unroll
            for (int r = 0; r < 4; ++r)
                G[((size_t)bb * S_ + row0 + r) * OUTC + col] = acc[mi][ni][r];
        }
    }
}

// ---------- 3) blend: C1[p] = sum_k w_k * G[b,i_k] (fp32) -> bf16 + BN1 stats ----------
__global__ __launch_bounds__(256) void blend1(
    const float* __restrict__ G, const int* __restrict__ idx, const float* __restrict__ wgt,
    ushort_t* __restrict__ C1, float* __restrict__ gsum, float* __restrict__ gsq)
{
    __shared__ float reds[512], redq[512];
    const int t = threadIdx.x;
    const int cg = t & 63, pr = t >> 6;
    const int ch0 = cg * 8;
    const int pBase = blockIdx.x * 128;

    float s[8], q[8];
#pragma unroll
    for (int e = 0; e < 8; ++e) { s[e] = 0.f; q[e] = 0.f; }

    for (int j = 0; j < 32; ++j) {
        const int p = pBase + j * 4 + pr;
        const int b = p >> 13;
        const int i0 = idx[p * 3 + 0], i1 = idx[p * 3 + 1], i2 = idx[p * 3 + 2];
        const float w0 = wgt[p * 3 + 0], w1 = wgt[p * 3 + 1], w2 = wgt[p * 3 + 2];
        const float* g0 = G + ((size_t)b * S_ + i0) * OUTC + ch0;
        const float* g1 = G + ((size_t)b * S_ + i1) * OUTC + ch0;
        const float* g2 = G + ((size_t)b * S_ + i2) * OUTC + ch0;
        float c[8];
        uint32_t od[4];
#pragma unroll
        for (int e = 0; e < 8; ++e) {
            c[e] = w0 * g0[e] + w1 * g1[e] + w2 * g2[e];
            s[e] += c[e]; q[e] += c[e] * c[e];
        }
#pragma unroll
        for (int e = 0; e < 4; ++e) od[e] = f2b(c[2 * e]) | (f2b(c[2 * e + 1]) << 16);
        uint4 o; o.x = od[0]; o.y = od[1]; o.z = od[2]; o.w = od[3];
        *(uint4*)(C1 + (size_t)p * OUTC + ch0) = o;
    }

    for (int i = t; i < 512; i += 256) { reds[i] = 0.f; redq[i] = 0.f; }
    __syncthreads();
#pragma unroll
    for (int e = 0; e < 8; ++e) {
        atomicAdd(&reds[ch0 + e], s[e]);
        atomicAdd(&redq[ch0 + e], q[e]);
    }
    __syncthreads();
    for (int i = t; i < 512; i += 256) {
        atomicAdd(&gsum[i], reds[i]);
        atomicAdd(&gsq[i],  redq[i]);
    }
}

// ---------- 5) BN1 finalize (inline) + apply + ReLU on bf16 C1 (in place) ----------
__global__ __launch_bounds__(256) void bn_apply_c1(
    ushort_t* __restrict__ X, const float* __restrict__ gsum, const float* __restrict__ gsq,
    const float* __restrict__ gamma, const float* __restrict__ beta)
{
    __shared__ float sc[512], sh[512];
    const int t = threadIdx.x;
    const float inv = 1.0f / (float)P_;
    for (int i = t; i < 512; i += 256) {
        const float mean = gsum[i] * inv;
        const float var  = gsq[i] * inv - mean * mean;
        const float s    = gamma[i] * rsqrtf(var + 1e-5f);
        sc[i] = s; sh[i] = beta[i] - mean * s;
    }
    __syncthreads();
    const size_t v = (size_t)blockIdx.x * 256 + t;
    uint4 xv = ((const uint4*)X)[v];
    const int ch = (int)((v * 8) & 511);
    uint32_t wsrc[4] = {xv.x, xv.y, xv.z, xv.w};
    uint32_t od[4];
#pragma unroll
    for (int j = 0; j < 4; ++j) {
        const int c0 = ch + 2 * j;
        const float y0 = fmaxf(0.f, b2f(wsrc[j] & 0xffffu) * sc[c0]     + sh[c0]);
        const float y1 = fmaxf(0.f, b2f(wsrc[j] >> 16)     * sc[c0 + 1] + sh[c0 + 1]);
        od[j] = f2b(y0) | (f2b(y1) << 16);
    }
    uint4 o; o.x = od[0]; o.y = od[1]; o.z = od[2]; o.w = od[3];
    ((uint4*)X)[v] = o;
}

// ---------- 6) GEMM2 (m97 global_load_lds staging): C1 x W2c^T + BN2 stats ----------
__global__ __launch_bounds__(256) void gemm2_stats(
    const ushort_t* __restrict__ A, const ushort_t* __restrict__ Bw,
    float* __restrict__ outF, ushort_t* __restrict__ outB, int out_bf16,
    float* __restrict__ gsum, float* __restrict__ gsq)
{
    __shared__ __align__(16) ushort_t Asm[128 * 32];   // 8 KB, NO padding (DMA layout)
    __shared__ __align__(16) ushort_t Bsm[128 * 32];
    __shared__ float red[256];
    const int K = 512, Nn = 512;
    const int t = threadIdx.x, wave = t >> 6, lane = t & 63;
    const int wr = wave >> 1, wc = wave & 1, quad = lane >> 4, l15 = lane & 15;
    const int rowBase = blockIdx.x * 128, colBase = blockIdx.y * 128;

    f32x4 acc[4][4];
    const f32x4 z4 = {0.f, 0.f, 0.f, 0.f};
#pragma unroll
    for (int i = 0; i < 4; ++i)
#pragma unroll
        for (int j = 0; j < 4; ++j) acc[i][j] = z4;

    const int ar0 = t >> 2, ac0 = (t & 3) * 8;
    const int ar1 = ar0 + 64;
    const ushort_t* Ab = A  + (size_t)rowBase * K;
    const ushort_t* Bb = Bw + (size_t)colBase * K;

    for (int k0 = 0; k0 < K; k0 += 32) {
        async16(Ab + (size_t)ar0 * K + k0 + ac0, &Asm[(size_t)t * 8]);
        async16(Ab + (size_t)ar1 * K + k0 + ac0, &Asm[(size_t)(t + 256) * 8]);
        async16(Bb + (size_t)ar0 * K + k0 + ac0, &Bsm[(size_t)t * 8]);
        async16(Bb + (size_t)ar1 * K + k0 + ac0, &Bsm[(size_t)(t + 256) * 8]);
        __syncthreads();

        s16x8 af[4], bfr[4];
#pragma unroll
        for (int mi = 0; mi < 4; ++mi)
            af[mi] = *(const s16x8*)&Asm[(wr * 64 + mi * 16 + l15) * 32 + quad * 8];
#pragma unroll
        for (int ni = 0; ni < 4; ++ni)
            bfr[ni] = *(const s16x8*)&Bsm[(wc * 64 + ni * 16 + l15) * 32 + quad * 8];
#pragma unroll
        for (int mi = 0; mi < 4; ++mi)
#pragma unroll
            for (int ni = 0; ni < 4; ++ni)
                acc[mi][ni] = __builtin_amdgcn_mfma_f32_16x16x32_bf16(
                    af[mi], bfr[ni], acc[mi][ni], 0, 0, 0);
        __syncthreads();
    }

    red[t] = 0.f;
    __syncthreads();
#pragma unroll
    for (int ni = 0; ni < 4; ++ni) {
        float s = 0.f, q = 0.f;
#pragma unroll
        for (int mi = 0; mi < 4; ++mi)
#pragma unroll
            for (int r = 0; r < 4; ++r) { const float v = acc[mi][ni][r]; s += v; q += v * v; }
        const int cl = wc * 64 + ni * 16 + l15;
        atomicAdd(&red[cl], s);
        atomicAdd(&red[128 + cl], q);
    }
    __syncthreads();
    if (t < 128) atomicAdd(&gsum[colBase + t], red[t]);
    else         atomicAdd(&gsq[colBase + (t - 128)], red[t]);

    if (out_bf16) {
#pragma unroll
        for (int mi = 0; mi < 4; ++mi) {
            const int row0 = rowBase + wr * 64 + mi * 16 + quad * 4;
#pragma unroll
            for (int ni = 0; ni < 4; ++ni) {
                const int col = colBase + wc * 64 + ni * 16 + l15;
#pragma unroll
                for (int r = 0; r < 4; ++r)
                    outB[(size_t)(row0 + r) * Nn + col] = (ushort_t)f2b(acc[mi][ni][r]);
            }
        }
    } else {
#pragma unroll
        for (int mi = 0; mi < 4; ++mi) {
            const int row0 = rowBase + wr * 64 + mi * 16 + quad * 4;
#pragma unroll
            for (int ni = 0; ni < 4; ++ni) {
                const int col = colBase + wc * 64 + ni * 16 + l15;
#pragma unroll
                for (int r = 0; r < 4; ++r)
                    outF[(size_t)(row0 + r) * Nn + col] = acc[mi][ni][r];
            }
        }
    }
}

// ---------- 7) BN2 finalize (inline) + apply + ReLU -> d_out fp32 ----------
__global__ __launch_bounds__(256) void bn_apply_out(
    const ushort_t* __restrict__ C2, float* __restrict__ Y,
    const float* __restrict__ gsum, const float* __restrict__ gsq,
    const float* __restrict__ gamma, const float* __restrict__ beta, int from_bf16)
{
    __shared__ float sc[512], sh[512];
    const int t = threadIdx.x;
    const float inv = 1.0f / (float)P_;
    for (int i = t; i < 512; i += 256) {
        const float mean = gsum[i] * inv;
        const float var  = gsq[i] * inv - mean * mean;
        const float s    = gamma[i] * rsqrtf(var + 1e-5f);
        sc[i] = s; sh[i] = beta[i] - mean * s;
    }
    __syncthreads();
    const size_t v = (size_t)blockIdx.x * 256 + t;   // 8 elems/thread
    const int ch = (int)((v * 8) & 511);
    float4 u0, u1;
    if (from_bf16) {
        const uint4 xv = ((const uint4*)C2)[v];
        u0.x = b2f(xv.x & 0xffffu); u0.y = b2f(xv.x >> 16);
        u0.z = b2f(xv.y & 0xffffu); u0.w = b2f(xv.y >> 16);
        u1.x = b2f(xv.z & 0xffffu); u1.y = b2f(xv.z >> 16);
        u1.z = b2f(xv.w & 0xffffu); u1.w = b2f(xv.w >> 16);
    } else {
        u0 = ((const float4*)Y)[v * 2];
        u1 = ((const float4*)Y)[v * 2 + 1];
    }
    u0.x = fmaxf(0.f, u0.x * sc[ch + 0] + sh[ch + 0]);
    u0.y = fmaxf(0.f, u0.y * sc[ch + 1] + sh[ch + 1]);
    u0.z = fmaxf(0.f, u0.z * sc[ch + 2] + sh[ch + 2]);
    u0.w = fmaxf(0.f, u0.w * sc[ch + 3] + sh[ch + 3]);
    u1.x = fmaxf(0.f, u1.x * sc[ch + 4] + sh[ch + 4]);
    u1.y = fmaxf(0.f, u1.y * sc[ch + 5] + sh[ch + 5]);
    u1.z = fmaxf(0.f, u1.z * sc[ch + 6] + sh[ch + 6]);
    u1.w = fmaxf(0.f, u1.w * sc[ch + 7] + sh[ch + 7]);
    ((float4*)Y)[v * 2]     = u0;
    ((float4*)Y)[v * 2 + 1] = u1;
}

// ---------- launch ----------
extern "C" void kernel_launch(void* const* d_in, const int* in_sizes, int n_in,
                              void* d_out, int out_size, void* d_ws, size_t ws_size,
                              hipStream_t stream)
{
    (void)in_sizes; (void)n_in; (void)out_size;
    const float* xyzF = (const float*)d_in[0];
    const float* cenF = (const float*)d_in[1];
    const float* H4   = (const float*)d_in[2];
    const float* H8   = (const float*)d_in[3];
    const float* H12  = (const float*)d_in[4];
    const float* W1f  = (const float*)d_in[5];
    // b1 (d_in[6]) / b2 (d_in[10]) cancel in BN mean subtraction
    const float* g1F  = (const float*)d_in[7];
    const float* be1F = (const float*)d_in[8];
    const float* W2f  = (const float*)d_in[9];
    const float* g2F  = (const float*)d_in[11];
    const float* be2F = (const float*)d_in[12];

    char* w = (char*)d_ws;
    float*    stats = (float*)w;     w += 2048 * 4;
    ushort_t* W1c   = (ushort_t*)w;  w += (size_t)OUTC * CIN * 2;
    ushort_t* W2c   = (ushort_t*)w;  w += (size_t)OUTC * OUTC * 2;
    int*      idxb  = (int*)w;       w += (size_t)P_ * 3 * 4;
    float*    wb    = (float*)w;     w += (size_t)P_ * 3 * 4;
    float*    G     = (float*)w;     w += (size_t)4 * S_ * OUTC * 4;   // 4 MB
    ushort_t* C1    = (ushort_t*)w;  w += (size_t)P_ * OUTC * 2;       // 32 MB
    const size_t need1 = (size_t)(w - (char*)d_ws);
    const int out_bf16 = (ws_size >= need1 + (size_t)P_ * OUTC * 2) ? 1 : 0;
    ushort_t* C2 = (ushort_t*)w;     // only used when out_bf16
    float* sum1 = stats, *sq1 = stats + 512, *sum2 = stats + 1024, *sq2 = stats + 1536;

    hipMemsetAsync(stats, 0, 2048 * 4, stream);
    prep_w<<<(OUTC * CIN / 4 + OUTC * OUTC / 4) / 256, 256, 0, stream>>>(W1f, W2f, W1c, W2c);
    knn_kernel<<<P_ / 64, 256, 0, stream>>>(xyzF, cenF, idxb, wb);
    gemm_g<<<dim3(8, 8, 4), 256, 0, stream>>>(H4, H8, H12, W1c, G);
    blend1<<<P_ / 128, 256, 0, stream>>>(G, idxb, wb, C1, sum1, sq1);
    bn_apply_c1<<<(P_ * OUTC / 8) / 256, 256, 0, stream>>>(C1, sum1, sq1, g1F, be1F);
    gemm2_stats<<<dim3(P_ / 128, 4), 256, 0, stream>>>(C1, W2c, (float*)d_out, C2,
                                                       out_bf16, sum2, sq2);
    bn_apply_out<<<(P_ * OUTC / 8) / 256, 256, 0, stream>>>(C2, (float*)d_out, sum2, sq2,
                                                            g2F, be2F, out_bf16);
}

// Round 6
// 257.845 us; speedup vs baseline: 1.2023x; 1.2023x over previous
//
#include <hip/hip_runtime.h>
#include <stdint.h>

#define S_   512
#define E_   512
#define CIN  1536
#define P_   32768
#define OUTC 512
#define LDP  40   // padded LDS stride (shorts) for register-staged gemm_g

typedef __attribute__((ext_vector_type(8))) short s16x8;   // MFMA A/B frag (8 bf16)
typedef __attribute__((ext_vector_type(4))) float f32x4;   // MFMA C/D frag
typedef unsigned short ushort_t;

__device__ __forceinline__ float b2f(uint32_t b) {
    union { uint32_t u; float f; } v; v.u = b << 16; return v.f;
}
__device__ __forceinline__ uint32_t f2b(float f) {   // fp32 -> bf16 bits, RNE
    union { float f; uint32_t u; } v; v.f = f;
    return (v.u + 0x7fffu + ((v.u >> 16) & 1u)) >> 16;
}
__device__ __forceinline__ uint4 cvt8(float4 a, float4 b) {
    uint4 r;
    r.x = f2b(a.x) | (f2b(a.y) << 16);
    r.y = f2b(a.z) | (f2b(a.w) << 16);
    r.z = f2b(b.x) | (f2b(b.y) << 16);
    r.w = f2b(b.z) | (f2b(b.w) << 16);
    return r;
}
__device__ __forceinline__ void async16(const void* g, void* l) {
    __builtin_amdgcn_global_load_lds(
        (const __attribute__((address_space(1))) void*)g,
        (__attribute__((address_space(3))) void*)l, 16, 0, 0);
}
// branchless top-3 insert: cmp + cndmask chains, no divergence
__device__ __forceinline__ void ins3(float d, int s,
                                     float& d0, int& i0, float& d1, int& i1,
                                     float& d2, int& i2)
{
    const bool c0 = d < d0, c1 = d < d1, c2 = d < d2;
    i2 = c1 ? i1 : (c2 ? s : i2);  d2 = c1 ? d1 : (c2 ? d : d2);
    i1 = c0 ? i0 : (c1 ? s : i1);  d1 = c0 ? d0 : (c1 ? d : d1);
    i0 = c0 ? s  : i0;             d0 = c0 ? d  : d0;
}

// ---------- 0) prep: W1,W2 fp32 -> bf16 ----------
__global__ __launch_bounds__(256) void prep_w(
    const float* __restrict__ W1f, const float* __restrict__ W2f,
    ushort_t* __restrict__ W1c, ushort_t* __restrict__ W2c)
{
    int v = blockIdx.x * 256 + threadIdx.x;          // vec4 index
    if (v < (OUTC * CIN / 4)) {
        const float4 x = ((const float4*)W1f)[v];
        uint2 o; o.x = f2b(x.x) | (f2b(x.y) << 16); o.y = f2b(x.z) | (f2b(x.w) << 16);
        ((uint2*)W1c)[v] = o;
    } else {
        v -= OUTC * CIN / 4;
        const float4 x = ((const float4*)W2f)[v];
        uint2 o; o.x = f2b(x.x) | (f2b(x.y) << 16); o.y = f2b(x.z) | (f2b(x.w) << 16);
        ((uint2*)W2c)[v] = o;
    }
}

// ---------- 1) kNN: 4 lanes/point, stride-4 interleaved scan, branchless ----------
__global__ __launch_bounds__(256) void knn_kernel(
    const float* __restrict__ xyz, const float* __restrict__ centers,
    int* __restrict__ idx_out, float* __restrict__ w_out)
{
    __shared__ float4 c4[S_];                // (x, y, z, |c|^2) -- one ds_read_b128
    const int t = threadIdx.x;
    const int pBlock = blockIdx.x * 64;      // 64 points per block; 64 | 8192
    const int b = pBlock >> 13;
    for (int i = t; i < S_; i += 256) {
        const float x = centers[(size_t)(b * S_ + i) * 3 + 0];
        const float y = centers[(size_t)(b * S_ + i) * 3 + 1];
        const float z = centers[(size_t)(b * S_ + i) * 3 + 2];
        float4 v; v.x = x; v.y = y; v.z = z; v.w = x * x + y * y + z * z;
        c4[i] = v;
    }
    __syncthreads();

    const int l4 = t & 3, pi = t >> 2;
    const int p = pBlock + pi;
    const float x = xyz[(size_t)p * 3 + 0];
    const float y = xyz[(size_t)p * 3 + 1];
    const float z = xyz[(size_t)p * 3 + 2];
    const float xx = x * x + y * y + z * z;

    float d0 = 3e38f, d1 = 3e38f, d2 = 3e38f;
    int   i0 = 0,     i1 = 0,     i2 = 0;
    // lane l4 scans s = 4j + l4: 4 lanes hit disjoint bank groups; 16 point-quads
    // in the wave broadcast the same 4 addresses -> conflict-free.
#pragma unroll 2
    for (int j = 0; j < 128; ++j) {
        const int s = 4 * j + l4;
        const float4 c = c4[s];
        const float dot = x * c.x + y * c.y + z * c.z;
        const float d = (xx - 2.0f * dot) + c.w;   // mirror np association
        ins3(d, s, d0, i0, d1, i1, d2, i2);
    }
    // merge 4 lane-local top-3 lists (xor 1 then xor 2), branchless
#pragma unroll
    for (int m = 1; m <= 2; m <<= 1) {
        const float od0 = __shfl_xor(d0, m), od1 = __shfl_xor(d1, m), od2 = __shfl_xor(d2, m);
        const int   oi0 = __shfl_xor(i0, m), oi1 = __shfl_xor(i1, m), oi2 = __shfl_xor(i2, m);
        ins3(od0, oi0, d0, i0, d1, i1, d2, i2);
        ins3(od1, oi1, d0, i0, d1, i1, d2, i2);
        ins3(od2, oi2, d0, i0, d1, i1, d2, i2);
    }
    if (l4 == 0) {
        const float r0 = 1.0f / (d0 + 1e-8f);
        const float r1 = 1.0f / (d1 + 1e-8f);
        const float r2 = 1.0f / (d2 + 1e-8f);
        const float rs = r0 + r1 + r2;
        idx_out[p * 3 + 0] = i0; idx_out[p * 3 + 1] = i1; idx_out[p * 3 + 2] = i2;
        w_out[p * 3 + 0] = r0 / rs; w_out[p * 3 + 1] = r1 / rs; w_out[p * 3 + 2] = r2 / rs;
    }
}

// ---------- 2) G[b] = concat(H)[b](512x1536 fp32) x W1c^T -> fp32 [4,512,512] ----------
// 64x64 tiles -> 256 blocks (full GPU); register double-buffer prefetch.
__global__ __launch_bounds__(256) void gemm_g(
    const float* __restrict__ H4, const float* __restrict__ H8,
    const float* __restrict__ H12, const ushort_t* __restrict__ W1c,
    float* __restrict__ G)
{
    __shared__ ushort_t Asm[64 * LDP];   // 5 KB
    __shared__ ushort_t Bsm[64 * LDP];
    const int t = threadIdx.x, wave = t >> 6, lane = t & 63;
    const int wr = wave >> 1, wc = wave & 1, quad = lane >> 4, l15 = lane & 15;
    const int bb = blockIdx.z;
    const int colBase = blockIdx.x * 64, rowBase = blockIdx.y * 64;
    const size_t hb = (size_t)bb * S_ * E_;

    f32x4 acc[2][2];
    const f32x4 z4 = {0.f, 0.f, 0.f, 0.f};
#pragma unroll
    for (int i = 0; i < 2; ++i)
#pragma unroll
        for (int j = 0; j < 2; ++j) acc[i][j] = z4;

    const int ar = t >> 2, ac = (t & 3) * 8;   // 256 slots = 64 rows x 32 k

    float4 A0a, A0b; uint4 B0;
    auto loadTile = [&](int k0) {
        const float* Hs = ((k0 < 512) ? H4 : (k0 < 1024) ? H8 : H12) + hb;
        const int kc = (k0 & 511) + ac;
        const float* r0 = Hs + (size_t)(rowBase + ar) * E_ + kc;
        A0a = *(const float4*)r0;  A0b = *(const float4*)(r0 + 4);
        B0  = *(const uint4*)(W1c + (size_t)(colBase + ar) * CIN + k0 + ac);
    };
    loadTile(0);

    for (int k0 = 0; k0 < CIN; k0 += 32) {
        __syncthreads();
        *(uint4*)&Asm[ar * LDP + ac] = cvt8(A0a, A0b);
        *(uint4*)&Bsm[ar * LDP + ac] = B0;
        __syncthreads();
        if (k0 + 32 < CIN) loadTile(k0 + 32);   // prefetch overlaps frag reads + MFMA

        s16x8 af[2], bfr[2];
#pragma unroll
        for (int mi = 0; mi < 2; ++mi)
            af[mi] = *(const s16x8*)&Asm[(wr * 32 + mi * 16 + l15) * LDP + quad * 8];
#pragma unroll
        for (int ni = 0; ni < 2; ++ni)
            bfr[ni] = *(const s16x8*)&Bsm[(wc * 32 + ni * 16 + l15) * LDP + quad * 8];
#pragma unroll
        for (int mi = 0; mi < 2; ++mi)
#pragma unroll
            for (int ni = 0; ni < 2; ++ni)
                acc[mi][ni] = __builtin_amdgcn_mfma_f32_16x16x32_bf16(
                    af[mi], bfr[ni], acc[mi][ni], 0, 0, 0);
    }

#pragma unroll
    for (int mi = 0; mi < 2; ++mi) {
        const int row0 = rowBase + wr * 32 + mi * 16 + quad * 4;
#pragma unroll
        for (int ni = 0; ni < 2; ++ni) {
            const int col = colBase + wc * 32 + ni * 16 + l15;
#pragma unroll
            for (int r = 0; r < 4; ++r)
                G[((size_t)bb * S_ + row0 + r) * OUTC + col] = acc[mi][ni][r];
        }
    }
}

// ---------- 3) blend: C1[p] = sum_k w_k * G[b,i_k] (fp32) -> bf16 + BN1 stats ----------
__global__ __launch_bounds__(256) void blend1(
    const float* __restrict__ G, const int* __restrict__ idx, const float* __restrict__ wgt,
    ushort_t* __restrict__ C1, float* __restrict__ gsum, float* __restrict__ gsq)
{
    __shared__ float reds[512], redq[512];
    const int t = threadIdx.x;
    const int cg = t & 63, pr = t >> 6;
    const int ch0 = cg * 8;
    const int pBase = blockIdx.x * 128;

    float s[8], q[8];
#pragma unroll
    for (int e = 0; e < 8; ++e) { s[e] = 0.f; q[e] = 0.f; }

    for (int j = 0; j < 32; ++j) {
        const int p = pBase + j * 4 + pr;
        const int b = p >> 13;
        const int i0 = idx[p * 3 + 0], i1 = idx[p * 3 + 1], i2 = idx[p * 3 + 2];
        const float w0 = wgt[p * 3 + 0], w1 = wgt[p * 3 + 1], w2 = wgt[p * 3 + 2];
        const float* g0 = G + ((size_t)b * S_ + i0) * OUTC + ch0;
        const float* g1 = G + ((size_t)b * S_ + i1) * OUTC + ch0;
        const float* g2 = G + ((size_t)b * S_ + i2) * OUTC + ch0;
        float c[8];
        uint32_t od[4];
#pragma unroll
        for (int e = 0; e < 8; ++e) {
            c[e] = w0 * g0[e] + w1 * g1[e] + w2 * g2[e];
            s[e] += c[e]; q[e] += c[e] * c[e];
        }
#pragma unroll
        for (int e = 0; e < 4; ++e) od[e] = f2b(c[2 * e]) | (f2b(c[2 * e + 1]) << 16);
        uint4 o; o.x = od[0]; o.y = od[1]; o.z = od[2]; o.w = od[3];
        *(uint4*)(C1 + (size_t)p * OUTC + ch0) = o;
    }

    for (int i = t; i < 512; i += 256) { reds[i] = 0.f; redq[i] = 0.f; }
    __syncthreads();
#pragma unroll
    for (int e = 0; e < 8; ++e) {
        atomicAdd(&reds[ch0 + e], s[e]);
        atomicAdd(&redq[ch0 + e], q[e]);
    }
    __syncthreads();
    for (int i = t; i < 512; i += 256) {
        atomicAdd(&gsum[i], reds[i]);
        atomicAdd(&gsq[i],  redq[i]);
    }
}

// ---------- 5) BN1 finalize (inline) + apply + ReLU on bf16 C1 (in place) ----------
__global__ __launch_bounds__(256) void bn_apply_c1(
    ushort_t* __restrict__ X, const float* __restrict__ gsum, const float* __restrict__ gsq,
    const float* __restrict__ gamma, const float* __restrict__ beta)
{
    __shared__ float sc[512], sh[512];
    const int t = threadIdx.x;
    const float inv = 1.0f / (float)P_;
    for (int i = t; i < 512; i += 256) {
        const float mean = gsum[i] * inv;
        const float var  = gsq[i] * inv - mean * mean;
        const float s    = gamma[i] * rsqrtf(var + 1e-5f);
        sc[i] = s; sh[i] = beta[i] - mean * s;
    }
    __syncthreads();
    const size_t v = (size_t)blockIdx.x * 256 + t;
    uint4 xv = ((const uint4*)X)[v];
    const int ch = (int)((v * 8) & 511);
    uint32_t wsrc[4] = {xv.x, xv.y, xv.z, xv.w};
    uint32_t od[4];
#pragma unroll
    for (int j = 0; j < 4; ++j) {
        const int c0 = ch + 2 * j;
        const float y0 = fmaxf(0.f, b2f(wsrc[j] & 0xffffu) * sc[c0]     + sh[c0]);
        const float y1 = fmaxf(0.f, b2f(wsrc[j] >> 16)     * sc[c0 + 1] + sh[c0 + 1]);
        od[j] = f2b(y0) | (f2b(y1) << 16);
    }
    uint4 o; o.x = od[0]; o.y = od[1]; o.z = od[2]; o.w = od[3];
    ((uint4*)X)[v] = o;
}

// ---------- 6) GEMM2 (m97 global_load_lds staging): C1 x W2c^T + BN2 stats ----------
__global__ __launch_bounds__(256) void gemm2_stats(
    const ushort_t* __restrict__ A, const ushort_t* __restrict__ Bw,
    float* __restrict__ outF, ushort_t* __restrict__ outB, int out_bf16,
    float* __restrict__ gsum, float* __restrict__ gsq)
{
    __shared__ __align__(16) ushort_t Asm[128 * 32];   // 8 KB, NO padding (DMA layout)
    __shared__ __align__(16) ushort_t Bsm[128 * 32];
    __shared__ float red[256];
    const int K = 512, Nn = 512;
    const int t = threadIdx.x, wave = t >> 6, lane = t & 63;
    const int wr = wave >> 1, wc = wave & 1, quad = lane >> 4, l15 = lane & 15;
    const int rowBase = blockIdx.x * 128, colBase = blockIdx.y * 128;

    f32x4 acc[4][4];
    const f32x4 z4 = {0.f, 0.f, 0.f, 0.f};
#pragma unroll
    for (int i = 0; i < 4; ++i)
#pragma unroll
        for (int j = 0; j < 4; ++j) acc[i][j] = z4;

    const int ar0 = t >> 2, ac0 = (t & 3) * 8;
    const int ar1 = ar0 + 64;
    const ushort_t* Ab = A  + (size_t)rowBase * K;
    const ushort_t* Bb = Bw + (size_t)colBase * K;

    for (int k0 = 0; k0 < K; k0 += 32) {
        async16(Ab + (size_t)ar0 * K + k0 + ac0, &Asm[(size_t)t * 8]);
        async16(Ab + (size_t)ar1 * K + k0 + ac0, &Asm[(size_t)(t + 256) * 8]);
        async16(Bb + (size_t)ar0 * K + k0 + ac0, &Bsm[(size_t)t * 8]);
        async16(Bb + (size_t)ar1 * K + k0 + ac0, &Bsm[(size_t)(t + 256) * 8]);
        __syncthreads();

        s16x8 af[4], bfr[4];
#pragma unroll
        for (int mi = 0; mi < 4; ++mi)
            af[mi] = *(const s16x8*)&Asm[(wr * 64 + mi * 16 + l15) * 32 + quad * 8];
#pragma unroll
        for (int ni = 0; ni < 4; ++ni)
            bfr[ni] = *(const s16x8*)&Bsm[(wc * 64 + ni * 16 + l15) * 32 + quad * 8];
#pragma unroll
        for (int mi = 0; mi < 4; ++mi)
#pragma unroll
            for (int ni = 0; ni < 4; ++ni)
                acc[mi][ni] = __builtin_amdgcn_mfma_f32_16x16x32_bf16(
                    af[mi], bfr[ni], acc[mi][ni], 0, 0, 0);
        __syncthreads();
    }

    red[t] = 0.f;
    __syncthreads();
#pragma unroll
    for (int ni = 0; ni < 4; ++ni) {
        float s = 0.f, q = 0.f;
#pragma unroll
        for (int mi = 0; mi < 4; ++mi)
#pragma unroll
            for (int r = 0; r < 4; ++r) { const float v = acc[mi][ni][r]; s += v; q += v * v; }
        const int cl = wc * 64 + ni * 16 + l15;
        atomicAdd(&red[cl], s);
        atomicAdd(&red[128 + cl], q);
    }
    __syncthreads();
    if (t < 128) atomicAdd(&gsum[colBase + t], red[t]);
    else         atomicAdd(&gsq[colBase + (t - 128)], red[t]);

    if (out_bf16) {
#pragma unroll
        for (int mi = 0; mi < 4; ++mi) {
            const int row0 = rowBase + wr * 64 + mi * 16 + quad * 4;
#pragma unroll
            for (int ni = 0; ni < 4; ++ni) {
                const int col = colBase + wc * 64 + ni * 16 + l15;
#pragma unroll
                for (int r = 0; r < 4; ++r)
                    outB[(size_t)(row0 + r) * Nn + col] = (ushort_t)f2b(acc[mi][ni][r]);
            }
        }
    } else {
#pragma unroll
        for (int mi = 0; mi < 4; ++mi) {
            const int row0 = rowBase + wr * 64 + mi * 16 + quad * 4;
#pragma unroll
            for (int ni = 0; ni < 4; ++ni) {
                const int col = colBase + wc * 64 + ni * 16 + l15;
#pragma unroll
                for (int r = 0; r < 4; ++r)
                    outF[(size_t)(row0 + r) * Nn + col] = acc[mi][ni][r];
            }
        }
    }
}

// ---------- 7) BN2 finalize (inline) + apply + ReLU -> d_out fp32 ----------
__global__ __launch_bounds__(256) void bn_apply_out(
    const ushort_t* __restrict__ C2, float* __restrict__ Y,
    const float* __restrict__ gsum, const float* __restrict__ gsq,
    const float* __restrict__ gamma, const float* __restrict__ beta, int from_bf16)
{
    __shared__ float sc[512], sh[512];
    const int t = threadIdx.x;
    const float inv = 1.0f / (float)P_;
    for (int i = t; i < 512; i += 256) {
        const float mean = gsum[i] * inv;
        const float var  = gsq[i] * inv - mean * mean;
        const float s    = gamma[i] * rsqrtf(var + 1e-5f);
        sc[i] = s; sh[i] = beta[i] - mean * s;
    }
    __syncthreads();
    const size_t v = (size_t)blockIdx.x * 256 + t;   // 8 elems/thread
    const int ch = (int)((v * 8) & 511);
    float4 u0, u1;
    if (from_bf16) {
        const uint4 xv = ((const uint4*)C2)[v];
        u0.x = b2f(xv.x & 0xffffu); u0.y = b2f(xv.x >> 16);
        u0.z = b2f(xv.y & 0xffffu); u0.w = b2f(xv.y >> 16);
        u1.x = b2f(xv.z & 0xffffu); u1.y = b2f(xv.z >> 16);
        u1.z = b2f(xv.w & 0xffffu); u1.w = b2f(xv.w >> 16);
    } else {
        u0 = ((const float4*)Y)[v * 2];
        u1 = ((const float4*)Y)[v * 2 + 1];
    }
    u0.x = fmaxf(0.f, u0.x * sc[ch + 0] + sh[ch + 0]);
    u0.y = fmaxf(0.f, u0.y * sc[ch + 1] + sh[ch + 1]);
    u0.z = fmaxf(0.f, u0.z * sc[ch + 2] + sh[ch + 2]);
    u0.w = fmaxf(0.f, u0.w * sc[ch + 3] + sh[ch + 3]);
    u1.x = fmaxf(0.f, u1.x * sc[ch + 4] + sh[ch + 4]);
    u1.y = fmaxf(0.f, u1.y * sc[ch + 5] + sh[ch + 5]);
    u1.z = fmaxf(0.f, u1.z * sc[ch + 6] + sh[ch + 6]);
    u1.w = fmaxf(0.f, u1.w * sc[ch + 7] + sh[ch + 7]);
    ((float4*)Y)[v * 2]     = u0;
    ((float4*)Y)[v * 2 + 1] = u1;
}

// ---------- launch ----------
extern "C" void kernel_launch(void* const* d_in, const int* in_sizes, int n_in,
                              void* d_out, int out_size, void* d_ws, size_t ws_size,
                              hipStream_t stream)
{
    (void)in_sizes; (void)n_in; (void)out_size;
    const float* xyzF = (const float*)d_in[0];
    const float* cenF = (const float*)d_in[1];
    const float* H4   = (const float*)d_in[2];
    const float* H8   = (const float*)d_in[3];
    const float* H12  = (const float*)d_in[4];
    const float* W1f  = (const float*)d_in[5];
    // b1 (d_in[6]) / b2 (d_in[10]) cancel in BN mean subtraction
    const float* g1F  = (const float*)d_in[7];
    const float* be1F = (const float*)d_in[8];
    const float* W2f  = (const float*)d_in[9];
    const float* g2F  = (const float*)d_in[11];
    const float* be2F = (const float*)d_in[12];

    char* w = (char*)d_ws;
    float*    stats = (float*)w;     w += 2048 * 4;
    ushort_t* W1c   = (ushort_t*)w;  w += (size_t)OUTC * CIN * 2;
    ushort_t* W2c   = (ushort_t*)w;  w += (size_t)OUTC * OUTC * 2;
    int*      idxb  = (int*)w;       w += (size_t)P_ * 3 * 4;
    float*    wb    = (float*)w;     w += (size_t)P_ * 3 * 4;
    float*    G     = (float*)w;     w += (size_t)4 * S_ * OUTC * 4;   // 4 MB
    ushort_t* C1    = (ushort_t*)w;  w += (size_t)P_ * OUTC * 2;       // 32 MB
    const size_t need1 = (size_t)(w - (char*)d_ws);
    const int out_bf16 = (ws_size >= need1 + (size_t)P_ * OUTC * 2) ? 1 : 0;
    ushort_t* C2 = (ushort_t*)w;     // only used when out_bf16
    float* sum1 = stats, *sq1 = stats + 512, *sum2 = stats + 1024, *sq2 = stats + 1536;

    hipMemsetAsync(stats, 0, 2048 * 4, stream);
    prep_w<<<(OUTC * CIN / 4 + OUTC * OUTC / 4) / 256, 256, 0, stream>>>(W1f, W2f, W1c, W2c);
    knn_kernel<<<P_ / 64, 256, 0, stream>>>(xyzF, cenF, idxb, wb);
    gemm_g<<<dim3(8, 8, 4), 256, 0, stream>>>(H4, H8, H12, W1c, G);
    blend1<<<P_ / 128, 256, 0, stream>>>(G, idxb, wb, C1, sum1, sq1);
    bn_apply_c1<<<(P_ * OUTC / 8) / 256, 256, 0, stream>>>(C1, sum1, sq1, g1F, be1F);
    gemm2_stats<<<dim3(P_ / 128, 4), 256, 0, stream>>>(C1, W2c, (float*)d_out, C2,
                                                       out_bf16, sum2, sq2);
    bn_apply_out<<<(P_ * OUTC / 8) / 256, 256, 0, stream>>>(C2, (float*)d_out, sum2, sq2,
                                                            g2F, be2F, out_bf16);
}

// Round 7
// 255.213 us; speedup vs baseline: 1.2147x; 1.0103x over previous
//
#include <hip/hip_runtime.h>
#include <stdint.h>

#define S_   512
#define E_   512
#define CIN  1536
#define P_   32768
#define OUTC 512
#define LDP  40    // padded LDS row stride (shorts) for register-staged tiles
#define CSTR 136   // epilogue C-staging row stride (shorts), 272B = 16B-aligned, 2-way max

typedef __attribute__((ext_vector_type(8))) short s16x8;   // MFMA A/B frag (8 bf16)
typedef __attribute__((ext_vector_type(4))) float f32x4;   // MFMA C/D frag
typedef unsigned short ushort_t;

__device__ __forceinline__ float b2f(uint32_t b) {
    union { uint32_t u; float f; } v; v.u = b << 16; return v.f;
}
__device__ __forceinline__ uint32_t f2b(float f) {   // fp32 -> bf16 bits, RNE
    union { float f; uint32_t u; } v; v.f = f;
    return (v.u + 0x7fffu + ((v.u >> 16) & 1u)) >> 16;
}
__device__ __forceinline__ uint4 cvt8(float4 a, float4 b) {
    uint4 r;
    r.x = f2b(a.x) | (f2b(a.y) << 16);
    r.y = f2b(a.z) | (f2b(a.w) << 16);
    r.z = f2b(b.x) | (f2b(b.y) << 16);
    r.w = f2b(b.z) | (f2b(b.w) << 16);
    return r;
}
__device__ __forceinline__ void async16(const void* g, void* l) {
    __builtin_amdgcn_global_load_lds(
        (const __attribute__((address_space(1))) void*)g,
        (__attribute__((address_space(3))) void*)l, 16, 0, 0);
}
// branchless top-3 insert
__device__ __forceinline__ void ins3(float d, int s,
                                     float& d0, int& i0, float& d1, int& i1,
                                     float& d2, int& i2)
{
    const bool c0 = d < d0, c1 = d < d1, c2 = d < d2;
    i2 = c1 ? i1 : (c2 ? s : i2);  d2 = c1 ? d1 : (c2 ? d : d2);
    i1 = c0 ? i0 : (c1 ? s : i1);  d1 = c0 ? d0 : (c1 ? d : d1);
    i0 = c0 ? s  : i0;             d0 = c0 ? d  : d0;
}

// ---------- 1) prologue: knn (blocks 0..511) + W1/W2 bf16 convert + stats zero ----------
__global__ __launch_bounds__(256) void prologue_kernel(
    const float* __restrict__ xyz, const float* __restrict__ centers,
    const float* __restrict__ W1f, const float* __restrict__ W2f,
    ushort_t* __restrict__ W1c, ushort_t* __restrict__ W2c,
    int* __restrict__ idx_out, float* __restrict__ w_out, float* __restrict__ stats)
{
    __shared__ float4 c4[S_];
    const int blk = blockIdx.x;
    const int t   = threadIdx.x;

    if (blk >= 512) {
        if (blk < 1280) {          // W1: 196608 vec4 over 768 blocks
            const int v = (blk - 512) * 256 + t;
            const float4 x = ((const float4*)W1f)[v];
            uint2 o; o.x = f2b(x.x) | (f2b(x.y) << 16); o.y = f2b(x.z) | (f2b(x.w) << 16);
            ((uint2*)W1c)[v] = o;
        } else if (blk < 1536) {   // W2: 65536 vec4 over 256 blocks
            const int v = (blk - 1280) * 256 + t;
            const float4 x = ((const float4*)W2f)[v];
            uint2 o; o.x = f2b(x.x) | (f2b(x.y) << 16); o.y = f2b(x.z) | (f2b(x.w) << 16);
            ((uint2*)W2c)[v] = o;
        } else {                    // zero 2048-float stats
#pragma unroll
            for (int i = 0; i < 8; ++i) stats[t * 8 + i] = 0.f;
        }
        return;
    }

    // ---- kNN: 4 lanes/point, stride-4 interleaved scan, branchless ----
    const int pBlock = blk * 64;
    const int b = pBlock >> 13;
    for (int i = t; i < S_; i += 256) {
        const float x = centers[(size_t)(b * S_ + i) * 3 + 0];
        const float y = centers[(size_t)(b * S_ + i) * 3 + 1];
        const float z = centers[(size_t)(b * S_ + i) * 3 + 2];
        float4 v; v.x = x; v.y = y; v.z = z; v.w = x * x + y * y + z * z;
        c4[i] = v;
    }
    __syncthreads();

    const int l4 = t & 3, pi = t >> 2;
    const int p = pBlock + pi;
    const float x = xyz[(size_t)p * 3 + 0];
    const float y = xyz[(size_t)p * 3 + 1];
    const float z = xyz[(size_t)p * 3 + 2];
    const float xx = x * x + y * y + z * z;

    float d0 = 3e38f, d1 = 3e38f, d2 = 3e38f;
    int   i0 = 0,     i1 = 0,     i2 = 0;
#pragma unroll 2
    for (int j = 0; j < 128; ++j) {
        const int s = 4 * j + l4;
        const float4 c = c4[s];
        const float dot = x * c.x + y * c.y + z * c.z;
        const float d = (xx - 2.0f * dot) + c.w;   // mirror np association
        ins3(d, s, d0, i0, d1, i1, d2, i2);
    }
#pragma unroll
    for (int m = 1; m <= 2; m <<= 1) {
        const float od0 = __shfl_xor(d0, m), od1 = __shfl_xor(d1, m), od2 = __shfl_xor(d2, m);
        const int   oi0 = __shfl_xor(i0, m), oi1 = __shfl_xor(i1, m), oi2 = __shfl_xor(i2, m);
        ins3(od0, oi0, d0, i0, d1, i1, d2, i2);
        ins3(od1, oi1, d0, i0, d1, i1, d2, i2);
        ins3(od2, oi2, d0, i0, d1, i1, d2, i2);
    }
    if (l4 == 0) {
        const float r0 = 1.0f / (d0 + 1e-8f);
        const float r1 = 1.0f / (d1 + 1e-8f);
        const float r2 = 1.0f / (d2 + 1e-8f);
        const float rs = r0 + r1 + r2;
        idx_out[p * 3 + 0] = i0; idx_out[p * 3 + 1] = i1; idx_out[p * 3 + 2] = i2;
        w_out[p * 3 + 0] = r0 / rs; w_out[p * 3 + 1] = r1 / rs; w_out[p * 3 + 2] = r2 / rs;
    }
}

// ---------- 2) G[b] = concat(H)[b](512x1536 fp32) x W1c^T -> fp32 [4,512,512] ----------
__global__ __launch_bounds__(256) void gemm_g(
    const float* __restrict__ H4, const float* __restrict__ H8,
    const float* __restrict__ H12, const ushort_t* __restrict__ W1c,
    float* __restrict__ G)
{
    __shared__ ushort_t Asm[64 * LDP];
    __shared__ ushort_t Bsm[64 * LDP];
    const int t = threadIdx.x, wave = t >> 6, lane = t & 63;
    const int wr = wave >> 1, wc = wave & 1, quad = lane >> 4, l15 = lane & 15;
    const int bb = blockIdx.z;
    const int colBase = blockIdx.x * 64, rowBase = blockIdx.y * 64;
    const size_t hb = (size_t)bb * S_ * E_;

    f32x4 acc[2][2];
    const f32x4 z4 = {0.f, 0.f, 0.f, 0.f};
#pragma unroll
    for (int i = 0; i < 2; ++i)
#pragma unroll
        for (int j = 0; j < 2; ++j) acc[i][j] = z4;

    const int ar = t >> 2, ac = (t & 3) * 8;

    float4 A0a, A0b; uint4 B0;
    auto loadTile = [&](int k0) {
        const float* Hs = ((k0 < 512) ? H4 : (k0 < 1024) ? H8 : H12) + hb;
        const int kc = (k0 & 511) + ac;
        const float* r0 = Hs + (size_t)(rowBase + ar) * E_ + kc;
        A0a = *(const float4*)r0;  A0b = *(const float4*)(r0 + 4);
        B0  = *(const uint4*)(W1c + (size_t)(colBase + ar) * CIN + k0 + ac);
    };
    loadTile(0);

    for (int k0 = 0; k0 < CIN; k0 += 32) {
        __syncthreads();
        *(uint4*)&Asm[ar * LDP + ac] = cvt8(A0a, A0b);
        *(uint4*)&Bsm[ar * LDP + ac] = B0;
        __syncthreads();
        if (k0 + 32 < CIN) loadTile(k0 + 32);

        s16x8 af[2], bfr[2];
#pragma unroll
        for (int mi = 0; mi < 2; ++mi)
            af[mi] = *(const s16x8*)&Asm[(wr * 32 + mi * 16 + l15) * LDP + quad * 8];
#pragma unroll
        for (int ni = 0; ni < 2; ++ni)
            bfr[ni] = *(const s16x8*)&Bsm[(wc * 32 + ni * 16 + l15) * LDP + quad * 8];
#pragma unroll
        for (int mi = 0; mi < 2; ++mi)
#pragma unroll
            for (int ni = 0; ni < 2; ++ni)
                acc[mi][ni] = __builtin_amdgcn_mfma_f32_16x16x32_bf16(
                    af[mi], bfr[ni], acc[mi][ni], 0, 0, 0);
    }

#pragma unroll
    for (int mi = 0; mi < 2; ++mi) {
        const int row0 = rowBase + wr * 32 + mi * 16 + quad * 4;
#pragma unroll
        for (int ni = 0; ni < 2; ++ni) {
            const int col = colBase + wc * 32 + ni * 16 + l15;
#pragma unroll
            for (int r = 0; r < 4; ++r)
                G[((size_t)bb * S_ + row0 + r) * OUTC + col] = acc[mi][ni][r];
        }
    }
}

// ---------- 3) blend: C1raw[p] = sum_k w_k * G[b,i_k] (fp32) -> bf16 + BN1 stats ----------
__global__ __launch_bounds__(256) void blend1(
    const float* __restrict__ G, const int* __restrict__ idx, const float* __restrict__ wgt,
    ushort_t* __restrict__ C1, float* __restrict__ gsum, float* __restrict__ gsq)
{
    __shared__ float reds[512], redq[512];
    const int t = threadIdx.x;
    const int cg = t & 63, pr = t >> 6;
    const int ch0 = cg * 8;
    const int pBase = blockIdx.x * 128;

    float s[8], q[8];
#pragma unroll
    for (int e = 0; e < 8; ++e) { s[e] = 0.f; q[e] = 0.f; }

    for (int j = 0; j < 32; ++j) {
        const int p = pBase + j * 4 + pr;
        const int b = p >> 13;
        const int i0 = idx[p * 3 + 0], i1 = idx[p * 3 + 1], i2 = idx[p * 3 + 2];
        const float w0 = wgt[p * 3 + 0], w1 = wgt[p * 3 + 1], w2 = wgt[p * 3 + 2];
        const float* g0 = G + ((size_t)b * S_ + i0) * OUTC + ch0;
        const float* g1 = G + ((size_t)b * S_ + i1) * OUTC + ch0;
        const float* g2 = G + ((size_t)b * S_ + i2) * OUTC + ch0;
        float c[8];
        uint32_t od[4];
#pragma unroll
        for (int e = 0; e < 8; ++e) {
            c[e] = w0 * g0[e] + w1 * g1[e] + w2 * g2[e];
            s[e] += c[e]; q[e] += c[e] * c[e];
        }
#pragma unroll
        for (int e = 0; e < 4; ++e) od[e] = f2b(c[2 * e]) | (f2b(c[2 * e + 1]) << 16);
        uint4 o; o.x = od[0]; o.y = od[1]; o.z = od[2]; o.w = od[3];
        *(uint4*)(C1 + (size_t)p * OUTC + ch0) = o;
    }

    for (int i = t; i < 512; i += 256) { reds[i] = 0.f; redq[i] = 0.f; }
    __syncthreads();
#pragma unroll
    for (int e = 0; e < 8; ++e) {
        atomicAdd(&reds[ch0 + e], s[e]);
        atomicAdd(&redq[ch0 + e], q[e]);
    }
    __syncthreads();
    for (int i = t; i < 512; i += 256) {
        atomicAdd(&gsum[i], reds[i]);
        atomicAdd(&gsq[i],  redq[i]);
    }
}

// ---------- 4) GEMM2 with fused BN1+ReLU on A and coalesced epilogue ----------
// A = raw C1 (bf16): a' = relu(a*sc1[c]+sh1[c]) applied during register staging.
// B = W2c via global_load_lds DMA.  Output + BN2 stats.
__global__ __launch_bounds__(256) void gemm2_fused(
    const ushort_t* __restrict__ Araw, const ushort_t* __restrict__ Bw,
    float* __restrict__ outF, ushort_t* __restrict__ outB, int out_bf16,
    const float* __restrict__ gsum1, const float* __restrict__ gsq1,
    const float* __restrict__ g1, const float* __restrict__ be1,
    float* __restrict__ gsum2, float* __restrict__ gsq2)
{
    __shared__ __align__(16) ushort_t sbuf[9216];   // Asm(5120) + Bsm(4096); epilogue reuse
    __shared__ float sc1[512], sh1[512];
    __shared__ float red[256];
    ushort_t* Asm = sbuf;                 // 128 x LDP(40), padded, register-staged
    ushort_t* Bsm = sbuf + 128 * LDP;     // 128 x 32, DMA layout (offset 10240B, 16B-aligned)

    const int K = 512, Nn = 512;
    const int t = threadIdx.x, wave = t >> 6, lane = t & 63;
    const int wr = wave >> 1, wc = wave & 1, quad = lane >> 4, l15 = lane & 15;
    const int rowBase = blockIdx.x * 128, colBase = blockIdx.y * 128;

    // BN1 finalize into LDS
    const float inv = 1.0f / (float)P_;
    for (int i = t; i < 512; i += 256) {
        const float mean = gsum1[i] * inv;
        const float var  = gsq1[i] * inv - mean * mean;
        const float s    = g1[i] * rsqrtf(var + 1e-5f);
        sc1[i] = s; sh1[i] = be1[i] - mean * s;
    }

    f32x4 acc[4][4];
    const f32x4 z4 = {0.f, 0.f, 0.f, 0.f};
#pragma unroll
    for (int i = 0; i < 4; ++i)
#pragma unroll
        for (int j = 0; j < 4; ++j) acc[i][j] = z4;

    const int ar0 = t >> 2, ac0 = (t & 3) * 8;
    const int ar1 = ar0 + 64;
    const ushort_t* Ab = Araw + (size_t)rowBase * K;
    const ushort_t* Bb = Bw   + (size_t)colBase * K;

    uint4 aR0 = *(const uint4*)(Ab + (size_t)ar0 * K + ac0);
    uint4 aR1 = *(const uint4*)(Ab + (size_t)ar1 * K + ac0);
    __syncthreads();    // sc1/sh1 visible

    for (int k0 = 0; k0 < K; k0 += 32) {
        // stage A with BN1+ReLU (fp32 math, RNE to bf16 -- identical to standalone pass)
        {
            const int cb = k0 + ac0;
            uint32_t wi[4] = {aR0.x, aR0.y, aR0.z, aR0.w};
            uint32_t wj[4] = {aR1.x, aR1.y, aR1.z, aR1.w};
            uint32_t oi[4], oj[4];
#pragma unroll
            for (int j = 0; j < 4; ++j) {
                const int c0 = cb + 2 * j;
                const float s0 = sc1[c0], h0 = sh1[c0], s1 = sc1[c0 + 1], h1 = sh1[c0 + 1];
                const float yi0 = fmaxf(0.f, b2f(wi[j] & 0xffffu) * s0 + h0);
                const float yi1 = fmaxf(0.f, b2f(wi[j] >> 16)     * s1 + h1);
                const float yj0 = fmaxf(0.f, b2f(wj[j] & 0xffffu) * s0 + h0);
                const float yj1 = fmaxf(0.f, b2f(wj[j] >> 16)     * s1 + h1);
                oi[j] = f2b(yi0) | (f2b(yi1) << 16);
                oj[j] = f2b(yj0) | (f2b(yj1) << 16);
            }
            uint4 u; u.x = oi[0]; u.y = oi[1]; u.z = oi[2]; u.w = oi[3];
            *(uint4*)&Asm[ar0 * LDP + ac0] = u;
            u.x = oj[0]; u.y = oj[1]; u.z = oj[2]; u.w = oj[3];
            *(uint4*)&Asm[ar1 * LDP + ac0] = u;
        }
        async16(Bb + (size_t)ar0 * K + k0 + ac0, &Bsm[(size_t)t * 8]);
        async16(Bb + (size_t)ar1 * K + k0 + ac0, &Bsm[(size_t)(t + 256) * 8]);
        __syncthreads();   // A written + B DMA drained

        if (k0 + 32 < K) {   // prefetch next A chunk (overlaps MFMA)
            aR0 = *(const uint4*)(Ab + (size_t)ar0 * K + k0 + 32 + ac0);
            aR1 = *(const uint4*)(Ab + (size_t)ar1 * K + k0 + 32 + ac0);
        }

        s16x8 af[4], bfr[4];
#pragma unroll
        for (int mi = 0; mi < 4; ++mi)
            af[mi] = *(const s16x8*)&Asm[(wr * 64 + mi * 16 + l15) * LDP + quad * 8];
#pragma unroll
        for (int ni = 0; ni < 4; ++ni)
            bfr[ni] = *(const s16x8*)&Bsm[(wc * 64 + ni * 16 + l15) * 32 + quad * 8];
#pragma unroll
        for (int mi = 0; mi < 4; ++mi)
#pragma unroll
            for (int ni = 0; ni < 4; ++ni)
                acc[mi][ni] = __builtin_amdgcn_mfma_f32_16x16x32_bf16(
                    af[mi], bfr[ni], acc[mi][ni], 0, 0, 0);
        __syncthreads();   // frag reads done before next stage overwrites
    }

    // ---- BN2 stats ----
    red[t] = 0.f;
    __syncthreads();
#pragma unroll
    for (int ni = 0; ni < 4; ++ni) {
        float s = 0.f, q = 0.f;
#pragma unroll
        for (int mi = 0; mi < 4; ++mi)
#pragma unroll
            for (int r = 0; r < 4; ++r) { const float v = acc[mi][ni][r]; s += v; q += v * v; }
        const int cl = wc * 64 + ni * 16 + l15;
        atomicAdd(&red[cl], s);
        atomicAdd(&red[128 + cl], q);
    }
    __syncthreads();
    if (t < 128) atomicAdd(&gsum2[colBase + t], red[t]);
    else         atomicAdd(&gsq2[colBase + (t - 128)], red[t]);

    // ---- store: LDS-staged coalesced (bf16 path) ----
    if (out_bf16) {
        ushort_t* cst = sbuf;          // 64 x CSTR(136) = 8704 shorts
        const int rr = t >> 2, seg = t & 3;
#pragma unroll
        for (int c = 0; c < 2; ++c) {
            __syncthreads();
            if (wr == c) {
#pragma unroll
                for (int mi = 0; mi < 4; ++mi)
#pragma unroll
                    for (int ni = 0; ni < 4; ++ni)
#pragma unroll
                        for (int r = 0; r < 4; ++r)
                            cst[(mi * 16 + quad * 4 + r) * CSTR + wc * 64 + ni * 16 + l15] =
                                (ushort_t)f2b(acc[mi][ni][r]);
            }
            __syncthreads();
            const size_t gbase = (size_t)(rowBase + c * 64 + rr) * Nn + colBase + seg * 32;
#pragma unroll
            for (int i = 0; i < 4; ++i) {
                const uint4 v = *(const uint4*)&cst[rr * CSTR + seg * 32 + i * 8];
                *(uint4*)(outB + gbase + i * 8) = v;
            }
        }
    } else {
#pragma unroll
        for (int mi = 0; mi < 4; ++mi) {
            const int row0 = rowBase + wr * 64 + mi * 16 + quad * 4;
#pragma unroll
            for (int ni = 0; ni < 4; ++ni) {
                const int col = colBase + wc * 64 + ni * 16 + l15;
#pragma unroll
                for (int r = 0; r < 4; ++r)
                    outF[(size_t)(row0 + r) * Nn + col] = acc[mi][ni][r];
            }
        }
    }
}

// ---------- 5) BN2 finalize (inline) + apply + ReLU -> d_out fp32 ----------
__global__ __launch_bounds__(256) void bn_apply_out(
    const ushort_t* __restrict__ C2, float* __restrict__ Y,
    const float* __restrict__ gsum, const float* __restrict__ gsq,
    const float* __restrict__ gamma, const float* __restrict__ beta, int from_bf16)
{
    __shared__ float sc[512], sh[512];
    const int t = threadIdx.x;
    const float inv = 1.0f / (float)P_;
    for (int i = t; i < 512; i += 256) {
        const float mean = gsum[i] * inv;
        const float var  = gsq[i] * inv - mean * mean;
        const float s    = gamma[i] * rsqrtf(var + 1e-5f);
        sc[i] = s; sh[i] = beta[i] - mean * s;
    }
    __syncthreads();
    const size_t v = (size_t)blockIdx.x * 256 + t;   // 8 elems/thread
    const int ch = (int)((v * 8) & 511);
    float4 u0, u1;
    if (from_bf16) {
        const uint4 xv = ((const uint4*)C2)[v];
        u0.x = b2f(xv.x & 0xffffu); u0.y = b2f(xv.x >> 16);
        u0.z = b2f(xv.y & 0xffffu); u0.w = b2f(xv.y >> 16);
        u1.x = b2f(xv.z & 0xffffu); u1.y = b2f(xv.z >> 16);
        u1.z = b2f(xv.w & 0xffffu); u1.w = b2f(xv.w >> 16);
    } else {
        u0 = ((const float4*)Y)[v * 2];
        u1 = ((const float4*)Y)[v * 2 + 1];
    }
    u0.x = fmaxf(0.f, u0.x * sc[ch + 0] + sh[ch + 0]);
    u0.y = fmaxf(0.f, u0.y * sc[ch + 1] + sh[ch + 1]);
    u0.z = fmaxf(0.f, u0.z * sc[ch + 2] + sh[ch + 2]);
    u0.w = fmaxf(0.f, u0.w * sc[ch + 3] + sh[ch + 3]);
    u1.x = fmaxf(0.f, u1.x * sc[ch + 4] + sh[ch + 4]);
    u1.y = fmaxf(0.f, u1.y * sc[ch + 5] + sh[ch + 5]);
    u1.z = fmaxf(0.f, u1.z * sc[ch + 6] + sh[ch + 6]);
    u1.w = fmaxf(0.f, u1.w * sc[ch + 7] + sh[ch + 7]);
    ((float4*)Y)[v * 2]     = u0;
    ((float4*)Y)[v * 2 + 1] = u1;
}

// ---------- launch ----------
extern "C" void kernel_launch(void* const* d_in, const int* in_sizes, int n_in,
                              void* d_out, int out_size, void* d_ws, size_t ws_size,
                              hipStream_t stream)
{
    (void)in_sizes; (void)n_in; (void)out_size;
    const float* xyzF = (const float*)d_in[0];
    const float* cenF = (const float*)d_in[1];
    const float* H4   = (const float*)d_in[2];
    const float* H8   = (const float*)d_in[3];
    const float* H12  = (const float*)d_in[4];
    const float* W1f  = (const float*)d_in[5];
    // b1 (d_in[6]) / b2 (d_in[10]) cancel in BN mean subtraction
    const float* g1F  = (const float*)d_in[7];
    const float* be1F = (const float*)d_in[8];
    const float* W2f  = (const float*)d_in[9];
    const float* g2F  = (const float*)d_in[11];
    const float* be2F = (const float*)d_in[12];

    char* w = (char*)d_ws;
    float*    stats = (float*)w;     w += 2048 * 4;
    ushort_t* W1c   = (ushort_t*)w;  w += (size_t)OUTC * CIN * 2;
    ushort_t* W2c   = (ushort_t*)w;  w += (size_t)OUTC * OUTC * 2;
    int*      idxb  = (int*)w;       w += (size_t)P_ * 3 * 4;
    float*    wb    = (float*)w;     w += (size_t)P_ * 3 * 4;
    float*    G     = (float*)w;     w += (size_t)4 * S_ * OUTC * 4;   // 4 MB
    ushort_t* C1    = (ushort_t*)w;  w += (size_t)P_ * OUTC * 2;       // 32 MB (raw, pre-BN)
    const size_t need1 = (size_t)(w - (char*)d_ws);
    const int out_bf16 = (ws_size >= need1 + (size_t)P_ * OUTC * 2) ? 1 : 0;
    ushort_t* C2 = (ushort_t*)w;     // only used when out_bf16
    float* sum1 = stats, *sq1 = stats + 512, *sum2 = stats + 1024, *sq2 = stats + 1536;

    prologue_kernel<<<1537, 256, 0, stream>>>(xyzF, cenF, W1f, W2f, W1c, W2c,
                                              idxb, wb, stats);
    gemm_g<<<dim3(8, 8, 4), 256, 0, stream>>>(H4, H8, H12, W1c, G);
    blend1<<<P_ / 128, 256, 0, stream>>>(G, idxb, wb, C1, sum1, sq1);
    gemm2_fused<<<dim3(P_ / 128, 4), 256, 0, stream>>>(C1, W2c, (float*)d_out, C2, out_bf16,
                                                       sum1, sq1, g1F, be1F, sum2, sq2);
    bn_apply_out<<<(P_ * OUTC / 8) / 256, 256, 0, stream>>>(C2, (float*)d_out, sum2, sq2,
                                                            g2F, be2F, out_bf16);
}